// Round 1
// baseline (408.764 us; speedup 1.0000x reference)
//
#include <hip/hip_runtime.h>

// ---------------------------------------------------------------------------
// SelfAttention: 3 projections (f32 [32768,1024] x [1024,64]^T + bias) with the
// reshape/transpose "view trick", then 64 causal attentions (L=512, D=64) with
// V_len key masking and Q_len output masking.
//
// Index algebra (verified): Y[b,l,d] -> head g=(b/16)*16 + (l%16),
//                                       seq  l2=(b%16)*32 + (l/16)
// out[x, l2, m*64+d] = O[g=x*16+m, l2, d] * (l2 < Q_len[x])
// ---------------------------------------------------------------------------

typedef _Float16 half8 __attribute__((ext_vector_type(8)));
typedef _Float16 half4v __attribute__((ext_vector_type(4)));
typedef float f32x4 __attribute__((ext_vector_type(4)));

#define LSEQ 512
#define ODIM 1024
#define NG   64           // g = x*16+m, 64 head-instances
#define HD   64           // head dim
#define GSTRIDE ((size_t)LSEQ * HD)   // per-g elements in ws tensors
#define TSIZE  ((size_t)NG * LSEQ * HD) // one projected tensor, 2,097,152 elems

// ---------------------------------------------------------------------------
// Projection GEMM: rows = 32768 (b*512+l), cols = 64, K = 1024.
// Tile 128x64 per workgroup, BK=32, mfma_f32_16x16x32_f16.
// LDS strides: A/W pad 32->40 halfs, C pad 64->72 halfs (16B-aligned frags).
// ---------------------------------------------------------------------------
__global__ __launch_bounds__(256) void proj_kernel(
    const float* __restrict__ Qs, const float* __restrict__ Ks,
    const float* __restrict__ Vs,
    const float* __restrict__ WQ, const float* __restrict__ bQ,
    const float* __restrict__ WK, const float* __restrict__ bK,
    const float* __restrict__ WV, const float* __restrict__ bV,
    _Float16* __restrict__ ws)
{
    const int p = blockIdx.y;
    const float* in; const float* W; const float* bias;
    if (p == 0)      { in = Qs; W = WQ; bias = bQ; }
    else if (p == 1) { in = Ks; W = WK; bias = bK; }
    else             { in = Vs; W = WV; bias = bV; }
    _Float16* outp = ws + (size_t)p * TSIZE;

    __shared__ _Float16 lds[9216];          // 18.4 KB
    _Float16* Al = lds;                     // 128 x 40
    _Float16* Wl = lds + 128 * 40;          // 64 x 40
    _Float16* Cl = lds;                     // 128 x 72 (aliases A/W after barrier)

    const int t    = threadIdx.x;
    const int lane = t & 63;
    const int w    = t >> 6;       // wave 0..3
    const int quad = lane >> 4;
    const int c    = lane & 15;

    const size_t rowBase = (size_t)blockIdx.x * 128;
    const float* Ag = in + rowBase * ODIM;

    f32x4 acc[2][4];
    #pragma unroll
    for (int i = 0; i < 2; ++i)
        #pragma unroll
        for (int j = 0; j < 4; ++j) { f32x4 z = {0.f,0.f,0.f,0.f}; acc[i][j] = z; }

    const int rr = t >> 3;          // 0..31
    const int c4 = (t & 7) * 4;     // 0..28

    for (int kt = 0; kt < 32; ++kt) {
        __syncthreads();
        // stage A tile: 128 x 32 f32 -> f16
        #pragma unroll
        for (int j = 0; j < 4; ++j) {
            int row = j * 32 + rr;
            float4 v = *(const float4*)(Ag + (size_t)row * ODIM + kt * 32 + c4);
            half4v h; h[0] = (_Float16)v.x; h[1] = (_Float16)v.y;
                      h[2] = (_Float16)v.z; h[3] = (_Float16)v.w;
            *(half4v*)&Al[row * 40 + c4] = h;
        }
        // stage W tile: 64 x 32
        #pragma unroll
        for (int j = 0; j < 2; ++j) {
            int row = j * 32 + rr;
            float4 v = *(const float4*)(W + (size_t)row * ODIM + kt * 32 + c4);
            half4v h; h[0] = (_Float16)v.x; h[1] = (_Float16)v.y;
                      h[2] = (_Float16)v.z; h[3] = (_Float16)v.w;
            *(half4v*)&Wl[row * 40 + c4] = h;
        }
        __syncthreads();

        half8 a0 = *(const half8*)&Al[(w * 32 + c) * 40 + quad * 8];
        half8 a1 = *(const half8*)&Al[(w * 32 + 16 + c) * 40 + quad * 8];
        #pragma unroll
        for (int ct = 0; ct < 4; ++ct) {
            half8 b = *(const half8*)&Wl[(ct * 16 + c) * 40 + quad * 8];
            acc[0][ct] = __builtin_amdgcn_mfma_f32_16x16x32_f16(a0, b, acc[0][ct], 0, 0, 0);
            acc[1][ct] = __builtin_amdgcn_mfma_f32_16x16x32_f16(a1, b, acc[1][ct], 0, 0, 0);
        }
    }

    // bias
    float bv[4];
    #pragma unroll
    for (int ct = 0; ct < 4; ++ct) bv[ct] = bias[ct * 16 + c];

    __syncthreads();   // done reading A/W; reuse as C
    #pragma unroll
    for (int rt = 0; rt < 2; ++rt)
        #pragma unroll
        for (int ct = 0; ct < 4; ++ct)
            #pragma unroll
            for (int r = 0; r < 4; ++r)
                Cl[(w * 32 + rt * 16 + quad * 4 + r) * 72 + ct * 16 + c] =
                    (_Float16)(acc[rt][ct][r] + bv[ct]);
    __syncthreads();

    // scatter-write to ws in [g][l2][d] layout, 16B chunks
    const int chunk = t & 7;
    #pragma unroll
    for (int j = 0; j < 4; ++j) {
        int row = j * 32 + rr;
        int n   = (int)rowBase + row;
        int b_i = n >> 9;          // n / 512
        int l   = n & 511;
        int g   = ((b_i >> 4) << 4) + (l & 15);
        int l2  = ((b_i & 15) << 5) + (l >> 4);
        half8 v = *(const half8*)&Cl[row * 72 + chunk * 8];
        *(half8*)(outp + ((size_t)g * LSEQ + l2) * HD + chunk * 8) = v;
    }
}

// ---------------------------------------------------------------------------
// Flash attention per (g, q-tile of 64). Online softmax, MFMA QK^T and PV.
// ---------------------------------------------------------------------------
__global__ __launch_bounds__(256) void attn_kernel(
    const _Float16* __restrict__ ws, const int* __restrict__ Qlen,
    const int* __restrict__ Vlen, float* __restrict__ out)
{
    const _Float16* Qws = ws;
    const _Float16* Kws = ws + TSIZE;
    const _Float16* Vws = ws + 2 * TSIZE;

    const int qt = blockIdx.x;      // 0..7
    const int g  = blockIdx.y;      // 0..63
    const int x  = g >> 4;
    const int m  = g & 15;
    const int qlen = Qlen[x];
    const int vlen = Vlen[x];
    const int q0 = qt * 64;

    const int t    = threadIdx.x;
    const int lane = t & 63;
    const int w    = t >> 6;
    const int quad = lane >> 4;
    const int c    = lane & 15;

    if (q0 >= qlen) {   // whole q-tile masked by Q_len -> zeros
        int row = t >> 2, d0 = (t & 3) * 16;
        float4 z = make_float4(0.f, 0.f, 0.f, 0.f);
        float* dst = out + ((size_t)(x * LSEQ + q0 + row)) * ODIM + m * 64 + d0;
        #pragma unroll
        for (int j = 0; j < 4; ++j) *(float4*)(dst + j * 4) = z;
        return;
    }

    __shared__ _Float16 Ql[64 * 72];
    __shared__ _Float16 Kl[64 * 72];
    __shared__ _Float16 Vt[64 * 72];        // transposed: [d][kk]
    __shared__ _Float16 Pl[4][16 * 72];     // per-wave P slice

    // stage Q tile
    {
        int row = t >> 2, d0 = (t & 3) * 16;
        const _Float16* src = Qws + ((size_t)g * LSEQ + q0 + row) * HD + d0;
        *(half8*)&Ql[row * 72 + d0]     = *(const half8*)src;
        *(half8*)&Ql[row * 72 + d0 + 8] = *(const half8*)(src + 8);
    }
    __syncthreads();
    const half8 aq0 = *(const half8*)&Ql[(w * 16 + c) * 72 + quad * 8];
    const half8 aq1 = *(const half8*)&Ql[(w * 16 + c) * 72 + 32 + quad * 8];

    f32x4 o[4];
    #pragma unroll
    for (int i = 0; i < 4; ++i) { f32x4 z = {0.f,0.f,0.f,0.f}; o[i] = z; }
    float mO[4], lO[4];
    #pragma unroll
    for (int r = 0; r < 4; ++r) { mO[r] = -1e30f; lO[r] = 0.f; }
    const int qrow_base = q0 + w * 16 + quad * 4;

    for (int kt = 0; kt <= qt; ++kt) {
        __syncthreads();   // prior iteration's K/V reads complete
        {
            int row = t >> 2, d0 = (t & 3) * 16;
            const _Float16* ksrc = Kws + ((size_t)g * LSEQ + kt * 64 + row) * HD + d0;
            *(half8*)&Kl[row * 72 + d0]     = *(const half8*)ksrc;
            *(half8*)&Kl[row * 72 + d0 + 8] = *(const half8*)(ksrc + 8);
            const _Float16* vsrc = Vws + ((size_t)g * LSEQ + kt * 64 + row) * HD + d0;
            half8 v0 = *(const half8*)vsrc;
            half8 v1 = *(const half8*)(vsrc + 8);
            #pragma unroll
            for (int j = 0; j < 8; ++j) {
                Vt[(d0 + j) * 72 + row]     = v0[j];
                Vt[(d0 + 8 + j) * 72 + row] = v1[j];
            }
        }
        __syncthreads();

        // S = Q K^T  (16 q-rows x 64 k-cols per wave)
        f32x4 s[4];
        #pragma unroll
        for (int ct = 0; ct < 4; ++ct) {
            half8 b0 = *(const half8*)&Kl[(ct * 16 + c) * 72 + quad * 8];
            half8 b1 = *(const half8*)&Kl[(ct * 16 + c) * 72 + 32 + quad * 8];
            f32x4 z = {0.f,0.f,0.f,0.f};
            z = __builtin_amdgcn_mfma_f32_16x16x32_f16(aq0, b0, z, 0, 0, 0);
            z = __builtin_amdgcn_mfma_f32_16x16x32_f16(aq1, b1, z, 0, 0, 0);
            s[ct] = z;
        }

        // scale + causal & V_len mask
        #pragma unroll
        for (int ct = 0; ct < 4; ++ct) {
            int kcol = kt * 64 + ct * 16 + c;
            #pragma unroll
            for (int r = 0; r < 4; ++r) {
                int qr = qrow_base + r;
                float sv = s[ct][r] * 0.125f;
                s[ct][r] = (kcol <= qr && kcol < vlen) ? sv : -1e30f;
            }
        }

        // online softmax update per row r
        #pragma unroll
        for (int r = 0; r < 4; ++r) {
            float v = fmaxf(fmaxf(s[0][r], s[1][r]), fmaxf(s[2][r], s[3][r]));
            v = fmaxf(v, __shfl_xor(v, 1, 64));
            v = fmaxf(v, __shfl_xor(v, 2, 64));
            v = fmaxf(v, __shfl_xor(v, 4, 64));
            v = fmaxf(v, __shfl_xor(v, 8, 64));
            float mn = fmaxf(mO[r], v);
            float alpha = __expf(mO[r] - mn);
            mO[r] = mn;
            float rs = 0.f;
            #pragma unroll
            for (int ct = 0; ct < 4; ++ct) {
                float pv = __expf(s[ct][r] - mn);
                s[ct][r] = pv;
                rs += pv;
            }
            rs += __shfl_xor(rs, 1, 64);
            rs += __shfl_xor(rs, 2, 64);
            rs += __shfl_xor(rs, 4, 64);
            rs += __shfl_xor(rs, 8, 64);
            lO[r] = lO[r] * alpha + rs;
            #pragma unroll
            for (int dct = 0; dct < 4; ++dct) o[dct][r] *= alpha;
        }

        // P: C-layout -> A-layout via per-wave LDS
        #pragma unroll
        for (int ct = 0; ct < 4; ++ct)
            #pragma unroll
            for (int r = 0; r < 4; ++r)
                Pl[w][(quad * 4 + r) * 72 + ct * 16 + c] = (_Float16)s[ct][r];

        half8 pa0 = *(const half8*)&Pl[w][c * 72 + quad * 8];
        half8 pa1 = *(const half8*)&Pl[w][c * 72 + 32 + quad * 8];
        #pragma unroll
        for (int dct = 0; dct < 4; ++dct) {
            half8 vb0 = *(const half8*)&Vt[(dct * 16 + c) * 72 + quad * 8];
            half8 vb1 = *(const half8*)&Vt[(dct * 16 + c) * 72 + 32 + quad * 8];
            o[dct] = __builtin_amdgcn_mfma_f32_16x16x32_f16(pa0, vb0, o[dct], 0, 0, 0);
            o[dct] = __builtin_amdgcn_mfma_f32_16x16x32_f16(pa1, vb1, o[dct], 0, 0, 0);
        }
    }

    // normalize + Q_len mask + store
    #pragma unroll
    for (int r = 0; r < 4; ++r) {
        int qr = qrow_base + r;
        float f = (qr < qlen) ? (1.0f / lO[r]) : 0.0f;
        #pragma unroll
        for (int dct = 0; dct < 4; ++dct)
            out[((size_t)(x * LSEQ + qr)) * ODIM + m * 64 + dct * 16 + c] =
                o[dct][r] * f;
    }
}

extern "C" void kernel_launch(void* const* d_in, const int* in_sizes, int n_in,
                              void* d_out, int out_size, void* d_ws, size_t ws_size,
                              hipStream_t stream) {
    const float* Qs  = (const float*)d_in[0];
    const float* Ks  = (const float*)d_in[1];
    const float* Vs  = (const float*)d_in[2];
    const int* Qlen  = (const int*)d_in[3];
    const int* Vlen  = (const int*)d_in[4];
    const float* WQ  = (const float*)d_in[5];
    const float* bQ  = (const float*)d_in[6];
    const float* WK  = (const float*)d_in[7];
    const float* bK  = (const float*)d_in[8];
    const float* WV  = (const float*)d_in[9];
    const float* bV  = (const float*)d_in[10];
    float* out = (float*)d_out;
    _Float16* ws = (_Float16*)d_ws;   // needs 3 * 2,097,152 * 2B = 12 MB

    proj_kernel<<<dim3(256, 3), 256, 0, stream>>>(Qs, Ks, Vs, WQ, bQ, WK, bK, WV, bV, ws);
    attn_kernel<<<dim3(8, 64), 256, 0, stream>>>(ws, Qlen, Vlen, out);
}